// Round 8
// baseline (119.301 us; speedup 1.0000x reference)
//
#include <hip/hip_runtime.h>
#include <stdint.h>

#define N_NODES 8192
#define NE      131072
#define DCH     128
#define WPR     256          // 32-bit words per bitmap row
#define MAXC    128          // per-node neighbor capacity (deg ~ Poisson(32), max ~60)
#define EPS     1e-5f

// ---------------------------------------------------------------------------
// Fused dispatch. Blocks [0,512): edges -> dedup bitmap (write-only) + direct
// compact neighbor-list append + exact deduped degree in cnt[]. Blocks
// [512,768): z = x @ W. Halves are independent -> no sync needed.
__global__ __launch_bounds__(256) void build_gemm_kernel(
    const void*  __restrict__ ei_raw,
    const float* __restrict__ X,
    const float* __restrict__ W,
    uint32_t* __restrict__ bm,
    int*      __restrict__ cnt,
    uint16_t* __restrict__ nbr,
    float*    __restrict__ z)
{
    int t = threadIdx.x;
    if (blockIdx.x < 512) {
        int lane = t & 63;
        const long long* p64 = (const long long*)ei_raw;
        const int*       p32 = (const int*)ei_raw;
        // layout detect: int32-packed data puts node ids in qword high halves
        bool is64 = __all((unsigned long long)p64[lane] < (unsigned long long)N_NODES);
        int e = blockIdx.x * 256 + t;
        int r, c;
        if (is64) { r = (int)p64[e]; c = (int)p64[NE + e]; }
        else      { r = p32[e];      c = p32[NE + e]; }
        uint32_t mc = 1u << (c & 31), mr = 1u << (r & 31);
        // bit-set idempotent => dedup (.at[].set semantics) + symmetrize free.
        // On a NEW bit, append to the compact list; cnt[] ends as deduped degree.
        uint32_t o1 = atomicOr(&bm[r * WPR + (c >> 5)], mc);
        if (!(o1 & mc)) {
            int pos = atomicAdd(&cnt[r], 1);
            if (pos < MAXC) nbr[(size_t)r * MAXC + pos] = (uint16_t)c;
        }
        uint32_t o2 = atomicOr(&bm[c * WPR + (r >> 5)], mr);
        if (!(o2 & mr)) {
            int pos = atomicAdd(&cnt[c], 1);
            if (pos < MAXC) nbr[(size_t)c * MAXC + pos] = (uint16_t)r;
        }
    } else {
        // ---- gemm: z = X @ W, 64x64 tile, 4x4/thread, f32 VALU (no fp32 MFMA).
        __shared__ float sA[64][132];
        int bx = blockIdx.x - 512;
        int row0 = (bx >> 1) * 64;
        int col0 = (bx & 1) * 64;
        {
            int k4 = t & 31;
            int r  = t >> 5;
            #pragma unroll
            for (int p = 0; p < 8; ++p) {
                float4 v = *(const float4*)&X[(size_t)(row0 + r + p * 8) * DCH + k4 * 4];
                *(float4*)&sA[r + p * 8][k4 * 4] = v;
            }
        }
        __syncthreads();
        int tx = t & 15, ty = t >> 4;
        int cg = col0 + tx * 4;
        int r0 = ty * 4;
        float acc[4][4] = {};
        #pragma unroll 4
        for (int k = 0; k < DCH; ++k) {
            float4 w = *(const float4*)&W[(size_t)k * DCH + cg];
            float a0 = sA[r0 + 0][k];
            float a1 = sA[r0 + 1][k];
            float a2 = sA[r0 + 2][k];
            float a3 = sA[r0 + 3][k];
            acc[0][0] += a0 * w.x; acc[0][1] += a0 * w.y; acc[0][2] += a0 * w.z; acc[0][3] += a0 * w.w;
            acc[1][0] += a1 * w.x; acc[1][1] += a1 * w.y; acc[1][2] += a1 * w.z; acc[1][3] += a1 * w.w;
            acc[2][0] += a2 * w.x; acc[2][1] += a2 * w.y; acc[2][2] += a2 * w.z; acc[2][3] += a2 * w.w;
            acc[3][0] += a3 * w.x; acc[3][1] += a3 * w.y; acc[3][2] += a3 * w.z; acc[3][3] += a3 * w.w;
        }
        #pragma unroll
        for (int i = 0; i < 4; ++i) {
            float4 o;
            o.x = acc[i][0]; o.y = acc[i][1]; o.z = acc[i][2]; o.w = acc[i][3];
            *(float4*)&z[(size_t)(row0 + r0 + i) * DCH + cg] = o;
        }
    }
}

// ---------------------------------------------------------------------------
// out[n] = dn * ( sum_j dj * z[j] + dn * z[n] ) + bias,  dj = rsqrt(cnt[j]+1+eps)
// Pure gather. One wave per node, lane = 2 channels (512B coalesced row
// loads), unroll-8 independent accumulators. Main loop UNPREDICATED (full
// 8-batches); one predicated batch handles the tail. j wave-uniform
// (readfirstlane) -> scalar row base + s_load for cnt[j].
__global__ __launch_bounds__(256) void aggregate_kernel(
    const uint16_t* __restrict__ nbr,
    const int*   __restrict__ cnt,
    const float* __restrict__ z,
    const float* __restrict__ bias,
    float*       __restrict__ out)
{
    __shared__ uint32_t s_list[4][64];   // 4 waves x 128 u16
    int w    = threadIdx.x >> 6;
    int lane = threadIdx.x & 63;
    int node = blockIdx.x * 4 + w;

    // wave-private staging: same-wave LDS ops are ordered, no barrier needed
    s_list[w][lane] = ((const uint32_t*)nbr)[(size_t)node * (MAXC / 2) + lane];
    const uint16_t* sl = (const uint16_t*)s_list[w];

    int total = __builtin_amdgcn_readfirstlane(cnt[node]);   // deduped degree
    int cap   = total > MAXC ? MAXC : total;
    int full  = cap & ~7;
    float dn  = 1.0f / sqrtf((float)total + 1.0f + EPS);     // rowsum(A_sym)+1

    const float2* z2 = (const float2*)z;
    float2 self = z2[(size_t)node * 64 + lane];
    float2 a0, a1 = {0,0}, a2 = {0,0}, a3 = {0,0}, a4 = {0,0}, a5 = {0,0}, a6 = {0,0}, a7 = {0,0};
    a0.x = dn * self.x; a0.y = dn * self.y;                  // +I self term

    // main loop: all 8 entries valid, no predication
    for (int k = 0; k < full; k += 8) {
        #define STEPU(i, AX) {                                                \
            int j = __builtin_amdgcn_readfirstlane((int)sl[k + i]);           \
            float dj = 1.0f / sqrtf((float)cnt[j] + 1.0f + EPS);              \
            float2 q = z2[(size_t)j * 64 + lane];                             \
            AX.x += dj * q.x; AX.y += dj * q.y; }
        STEPU(0, a0) STEPU(1, a1) STEPU(2, a2) STEPU(3, a3)
        STEPU(4, a4) STEPU(5, a5) STEPU(6, a6) STEPU(7, a7)
        #undef STEPU
    }
    // tail: single predicated batch of 8 (entries >= cap are garbage: clamp
    // j to node BEFORE address use, zero dj)
    if (full < cap) {
        #define STEPP(i, AX) {                                                \
            int idx = full + i;                                               \
            int j = __builtin_amdgcn_readfirstlane((int)sl[idx]);             \
            bool val = idx < cap;                                             \
            j = val ? j : node;                                               \
            float dj = val ? 1.0f / sqrtf((float)cnt[j] + 1.0f + EPS) : 0.0f; \
            float2 q = z2[(size_t)j * 64 + lane];                             \
            AX.x += dj * q.x; AX.y += dj * q.y; }
        STEPP(0, a0) STEPP(1, a1) STEPP(2, a2) STEPP(3, a3)
        STEPP(4, a4) STEPP(5, a5) STEPP(6, a6) STEPP(7, a7)
        #undef STEPP
    }

    float2 bb = ((const float2*)bias)[lane];
    float2 r;
    r.x = dn * (((a0.x + a1.x) + (a2.x + a3.x)) + ((a4.x + a5.x) + (a6.x + a7.x))) + bb.x;
    r.y = dn * (((a0.y + a1.y) + (a2.y + a3.y)) + ((a4.y + a5.y) + (a6.y + a7.y))) + bb.y;
    ((float2*)out)[(size_t)node * 64 + lane] = r;
}

// ---------------------------------------------------------------------------
extern "C" void kernel_launch(void* const* d_in, const int* in_sizes, int n_in,
                              void* d_out, int out_size, void* d_ws, size_t ws_size,
                              hipStream_t stream) {
    const float* xp  = (const float*)d_in[0];
    const void*  eip = d_in[1];
    const float* Wp  = (const float*)d_in[2];
    const float* bp  = (const float*)d_in[3];
    float*       op  = (float*)d_out;

    uint8_t* ws = (uint8_t*)d_ws;
    uint32_t* bmp  = (uint32_t*)ws;                                            // 8 MB
    int*      cntp = (int*)     (ws + (size_t)8 * 1024 * 1024);                // 32 KB
    uint16_t* nbrp = (uint16_t*)(ws + (size_t)8 * 1024 * 1024 + 32 * 1024);    // 2 MB
    float*    zp   = (float*)   (ws + (size_t)10 * 1024 * 1024 + 32 * 1024);   // 4 MB

    // one fill covers bitmap + cnt (contiguous)
    hipMemsetAsync(bmp, 0, (size_t)8 * 1024 * 1024 + 32 * 1024, stream);
    build_gemm_kernel<<<768, 256, 0, stream>>>(eip, xp, Wp, bmp, cntp, nbrp, zp);
    aggregate_kernel<<<N_NODES / 4, 256, 0, stream>>>(nbrp, cntp, zp, bp, op);
}

// Round 13
// 112.327 us; speedup vs baseline: 1.0621x; 1.0621x over previous
//
#include <hip/hip_runtime.h>
#include <stdint.h>

#define N_NODES 8192
#define NE      131072
#define DCH     128
#define WPR     256          // 32-bit words per bitmap row
#define MAXC    128          // per-node neighbor capacity (deg ~ Poisson(32), max ~60)
#define ZROW    8192         // dummy node id -> zero row of y (pad target)
#define EPS     1e-5f

// ---------------------------------------------------------------------------
// Fused dispatch. Blocks [0,512): edges -> dedup bitmap (write-only) + direct
// compact neighbor-list append + exact deduped degree in cnt[]. Blocks
// [512,768): z = x @ W (graph-independent). No sync needed between halves.
__global__ __launch_bounds__(256) void build_gemm_kernel(
    const void*  __restrict__ ei_raw,
    const float* __restrict__ X,
    const float* __restrict__ W,
    uint32_t* __restrict__ bm,
    int*      __restrict__ cnt,
    uint16_t* __restrict__ nbr,
    float*    __restrict__ z)
{
    int t = threadIdx.x;
    if (blockIdx.x < 512) {
        int lane = t & 63;
        const long long* p64 = (const long long*)ei_raw;
        const int*       p32 = (const int*)ei_raw;
        // layout detect: int32-packed data puts node ids in qword high halves
        bool is64 = __all((unsigned long long)p64[lane] < (unsigned long long)N_NODES);
        int e = blockIdx.x * 256 + t;
        int r, c;
        if (is64) { r = (int)p64[e]; c = (int)p64[NE + e]; }
        else      { r = p32[e];      c = p32[NE + e]; }
        uint32_t mc = 1u << (c & 31), mr = 1u << (r & 31);
        // bit-set idempotent => dedup (.at[].set semantics) + symmetrize free.
        // On a NEW bit, append to the compact list; cnt[] ends as deduped degree.
        uint32_t o1 = atomicOr(&bm[r * WPR + (c >> 5)], mc);
        if (!(o1 & mc)) {
            int pos = atomicAdd(&cnt[r], 1);
            if (pos < MAXC) nbr[(size_t)r * MAXC + pos] = (uint16_t)c;
        }
        uint32_t o2 = atomicOr(&bm[c * WPR + (r >> 5)], mr);
        if (!(o2 & mr)) {
            int pos = atomicAdd(&cnt[c], 1);
            if (pos < MAXC) nbr[(size_t)c * MAXC + pos] = (uint16_t)r;
        }
    } else {
        // ---- gemm: z = X @ W, 64x64 tile, 4x4/thread, f32 VALU (no fp32 MFMA).
        __shared__ float sA[64][132];
        int bx = blockIdx.x - 512;
        int row0 = (bx >> 1) * 64;
        int col0 = (bx & 1) * 64;
        {
            int k4 = t & 31;
            int r  = t >> 5;
            #pragma unroll
            for (int p = 0; p < 8; ++p) {
                float4 v = *(const float4*)&X[(size_t)(row0 + r + p * 8) * DCH + k4 * 4];
                *(float4*)&sA[r + p * 8][k4 * 4] = v;
            }
        }
        __syncthreads();
        int tx = t & 15, ty = t >> 4;
        int cg = col0 + tx * 4;
        int r0 = ty * 4;
        float acc[4][4] = {};
        #pragma unroll 4
        for (int k = 0; k < DCH; ++k) {
            float4 w = *(const float4*)&W[(size_t)k * DCH + cg];
            float a0 = sA[r0 + 0][k];
            float a1 = sA[r0 + 1][k];
            float a2 = sA[r0 + 2][k];
            float a3 = sA[r0 + 3][k];
            acc[0][0] += a0 * w.x; acc[0][1] += a0 * w.y; acc[0][2] += a0 * w.z; acc[0][3] += a0 * w.w;
            acc[1][0] += a1 * w.x; acc[1][1] += a1 * w.y; acc[1][2] += a1 * w.z; acc[1][3] += a1 * w.w;
            acc[2][0] += a2 * w.x; acc[2][1] += a2 * w.y; acc[2][2] += a2 * w.z; acc[2][3] += a2 * w.w;
            acc[3][0] += a3 * w.x; acc[3][1] += a3 * w.y; acc[3][2] += a3 * w.z; acc[3][3] += a3 * w.w;
        }
        #pragma unroll
        for (int i = 0; i < 4; ++i) {
            float4 o;
            o.x = acc[i][0]; o.y = acc[i][1]; o.z = acc[i][2]; o.w = acc[i][3];
            *(float4*)&z[(size_t)(row0 + r0 + i) * DCH + cg] = o;
        }
    }
}

// ---------------------------------------------------------------------------
// Finish: per node (1 wave each) compute dinv, pad neighbor list to x8 with
// ZROW, and prescale y[n] = dinv[n] * z[n]. Also zero y[ZROW] so padded
// entries contribute exactly 0 in the aggregate. ~8 MB traffic total.
__global__ __launch_bounds__(256) void finish_kernel(
    const int*   __restrict__ cnt,
    uint16_t*    __restrict__ nbr,
    const float* __restrict__ z,
    float*       __restrict__ y,
    float*       __restrict__ dinv)
{
    int w    = threadIdx.x >> 6;
    int lane = threadIdx.x & 63;
    int node = blockIdx.x * 4 + w;

    int total = __builtin_amdgcn_readfirstlane(cnt[node]);   // deduped degree
    int cap   = total > MAXC ? MAXC : total;
    int kpad  = (cap + 7) & ~7;
    float dn  = 1.0f / sqrtf((float)total + 1.0f + EPS);     // rowsum(A_sym)+1 (the +I)

    if (lane == 0) dinv[node] = dn;
    if (lane < 8 && cap + lane < kpad)
        nbr[(size_t)node * MAXC + cap + lane] = (uint16_t)ZROW;

    const float2* z2 = (const float2*)z;
    float2*       y2 = (float2*)y;
    float2 v = z2[(size_t)node * 64 + lane];
    float2 s; s.x = dn * v.x; s.y = dn * v.y;
    y2[(size_t)node * 64 + lane] = s;

    if (node == 0) { float2 zz = {0.0f, 0.0f}; y2[(size_t)ZROW * 64 + lane] = zz; }
}

// ---------------------------------------------------------------------------
// out[n] = dn * ( sum_{k<kpad} y[nbr[n][k]] + y[n] ) + bias
// Pure prescaled gather (zero per-neighbor arithmetic — the R4-measured-fast
// form). One wave per node, lane = 2 channels (512B coalesced row loads),
// unroll-8 independent accumulators, fully unpredicated (ZROW pad rows = 0).
__global__ __launch_bounds__(256) void aggregate_kernel(
    const uint16_t* __restrict__ nbr,
    const int*   __restrict__ cnt,
    const float* __restrict__ dinv,
    const float* __restrict__ y,
    const float* __restrict__ bias,
    float*       __restrict__ out)
{
    __shared__ uint32_t s_list[4][64];   // 4 waves x 128 u16
    int w    = threadIdx.x >> 6;
    int lane = threadIdx.x & 63;
    int node = blockIdx.x * 4 + w;

    // wave-private staging: same-wave LDS ops are ordered, no barrier needed
    s_list[w][lane] = ((const uint32_t*)nbr)[(size_t)node * (MAXC / 2) + lane];
    const uint16_t* sl = (const uint16_t*)s_list[w];

    int total = __builtin_amdgcn_readfirstlane(cnt[node]);
    int cap   = total > MAXC ? MAXC : total;
    int kpad  = (cap + 7) & ~7;
    float dn  = dinv[node];

    const float2* y2 = (const float2*)y;
    float2 a0 = y2[(size_t)node * 64 + lane];   // +I self term (prescaled)
    float2 a1 = {0,0}, a2 = {0,0}, a3 = {0,0}, a4 = {0,0}, a5 = {0,0}, a6 = {0,0}, a7 = {0,0};

    for (int k = 0; k < kpad; k += 8) {
        #define STEPU(i, AX) {                                      \
            int j = __builtin_amdgcn_readfirstlane((int)sl[k + i]); \
            float2 q = y2[(size_t)j * 64 + lane];                   \
            AX.x += q.x; AX.y += q.y; }
        STEPU(0, a0) STEPU(1, a1) STEPU(2, a2) STEPU(3, a3)
        STEPU(4, a4) STEPU(5, a5) STEPU(6, a6) STEPU(7, a7)
        #undef STEPU
    }

    float2 bb = ((const float2*)bias)[lane];
    float2 r;
    r.x = dn * (((a0.x + a1.x) + (a2.x + a3.x)) + ((a4.x + a5.x) + (a6.x + a7.x))) + bb.x;
    r.y = dn * (((a0.y + a1.y) + (a2.y + a3.y)) + ((a4.y + a5.y) + (a6.y + a7.y))) + bb.y;
    ((float2*)out)[(size_t)node * 64 + lane] = r;
}

// ---------------------------------------------------------------------------
extern "C" void kernel_launch(void* const* d_in, const int* in_sizes, int n_in,
                              void* d_out, int out_size, void* d_ws, size_t ws_size,
                              hipStream_t stream) {
    const float* xp  = (const float*)d_in[0];
    const void*  eip = d_in[1];
    const float* Wp  = (const float*)d_in[2];
    const float* bp  = (const float*)d_in[3];
    float*       op  = (float*)d_out;

    uint8_t* ws = (uint8_t*)d_ws;
    uint32_t* bmp   = (uint32_t*)ws;                                   // 8 MB      @ 0
    int*      cntp  = (int*)     (ws + 8388608);                       // 32 KB     @ 8 MB
    uint16_t* nbrp  = (uint16_t*)(ws + 8421376);                       // 2 MB
    float*    zp    = (float*)   (ws + 10518528);                      // 4 MB
    float*    yp    = (float*)   (ws + 14712832);                      // 4 MB + 512B (8193 rows)
    float*    dinvp = (float*)   (ws + 18907648);                      // 32 KB

    // one fill covers bitmap + cnt (contiguous)
    hipMemsetAsync(bmp, 0, 8388608 + 32768, stream);
    build_gemm_kernel<<<768, 256, 0, stream>>>(eip, xp, Wp, bmp, cntp, nbrp, zp);
    finish_kernel<<<N_NODES / 4, 256, 0, stream>>>(cntp, nbrp, zp, yp, dinvp);
    aggregate_kernel<<<N_NODES / 4, 256, 0, stream>>>(nbrp, cntp, dinvp, yp, bp, op);
}